// Round 1
// baseline (212.631 us; speedup 1.0000x reference)
//
#include <hip/hip_runtime.h>

#define KD 1536
#define ND 3072
#define MD 784
#define MPAD 832
#define TT 16

typedef __attribute__((ext_vector_type(8))) short short8;
typedef __attribute__((ext_vector_type(4))) float floatx4;

__device__ __forceinline__ unsigned short f2bf(float f) {
    unsigned int x = __float_as_uint(f);
    unsigned int r = (x + 0x7fffu + ((x >> 16) & 1u)) >> 16;
    return (unsigned short)r;
}

// ---------------- pack A: y (fp32, [c][t][14][14]) -> Ap bf16 [MPAD][KD], m=t*49+i*7+j, A[m][k]=y[k][t][2i][2j]
__global__ __launch_bounds__(256) void packA_k(const float* __restrict__ y,
                                               unsigned short* __restrict__ Ap) {
    int m = blockIdx.x;           // 0..831
    int tid = threadIdx.x;
    if (m >= MD) {
        for (int k = tid; k < KD; k += 256) Ap[(size_t)m * KD + k] = 0;
        return;
    }
    int t = m / 49, ij = m % 49, i = ij / 7, j = ij % 7;
    int off = t * 196 + (2 * i) * 14 + 2 * j;
    for (int k = tid; k < KD; k += 256)
        Ap[(size_t)m * KD + k] = f2bf(y[(size_t)k * 3136 + off]);
}

// ---------------- pack B: conv_w fp32 [o][c] -> bf16 [ND][KD] (k contiguous = B^T, MFMA-ready)
__global__ __launch_bounds__(256) void packB_k(const float* __restrict__ w,
                                               unsigned short* __restrict__ Bp) {
    size_t i4 = ((size_t)blockIdx.x * 256 + threadIdx.x) * 4;
    float4 v = *(const float4*)(w + i4);
    ushort4 o;
    o.x = f2bf(v.x); o.y = f2bf(v.y); o.z = f2bf(v.z); o.w = f2bf(v.w);
    *(ushort4*)(Bp + i4) = o;
}

// ---------------- ROI align: x_t [o][t][14][14] -> mr [m][ND]  (m = t*49 + i*7 + j)
__global__ __launch_bounds__(256) void roi_k(const float* __restrict__ x_t,
                                             const float* __restrict__ rois,
                                             float* __restrict__ mr) {
    __shared__ float sm[64 * 197];
    __shared__ float wx0s[14], wx1s[14], wy0s[14], wy1s[14];
    __shared__ int x0s[14], x1s[14], y0s[14], y1s[14], vxs[14], vys[14];
    const int t = blockIdx.y;
    const int o0 = blockIdx.x * 64;
    const int tid = threadIdx.x;

    if (tid < 14) {
        float b0 = rois[t * 4 + 0] * 0.0625f, b1 = rois[t * 4 + 1] * 0.0625f;
        float b2 = rois[t * 4 + 2] * 0.0625f, b3 = rois[t * 4 + 3] * 0.0625f;
        float rw = fmaxf(b2 - b0, 1.0f), rh = fmaxf(b3 - b1, 1.0f);
        float bw = rw * (1.0f / 7.0f), bh = rh * (1.0f / 7.0f);
        int p = tid;
        float pos = (float)(p >> 1) + 0.25f + 0.5f * (float)(p & 1);
        float xs = b0 + pos * bw;
        float ysv = b1 + pos * bh;
        vxs[p] = (xs >= -1.0f && xs <= 14.0f);
        vys[p] = (ysv >= -1.0f && ysv <= 14.0f);
        float xc = fminf(fmaxf(xs, 0.0f), 13.0f);
        float yc = fminf(fmaxf(ysv, 0.0f), 13.0f);
        int x0 = (int)floorf(xc), y0 = (int)floorf(yc);
        x0s[p] = x0; y0s[p] = y0;
        x1s[p] = min(x0 + 1, 13); y1s[p] = min(y0 + 1, 13);
        float lx = xc - (float)x0, ly = yc - (float)y0;
        wx0s[p] = 1.0f - lx; wx1s[p] = lx; wy0s[p] = 1.0f - ly; wy1s[p] = ly;
    }
    for (int f = tid; f < 64 * 196; f += 256) {
        int c = f / 196, pix = f % 196;
        sm[c * 197 + pix] = x_t[(size_t)(o0 + c) * 3136 + t * 196 + pix];
    }
    __syncthreads();
    for (int item = tid; item < 64 * 49; item += 256) {
        int c = item & 63, ij = item >> 6;
        int i = ij / 7, j = ij % 7;
        const float* base = &sm[c * 197];
        float sum = 0.0f;
#pragma unroll
        for (int s = 0; s < 2; ++s) {
            int p = 2 * i + s;
#pragma unroll
            for (int u = 0; u < 2; ++u) {
                int q = 2 * j + u;
                if (vys[p] && vxs[q]) {
                    float v00 = base[y0s[p] * 14 + x0s[q]];
                    float v01 = base[y0s[p] * 14 + x1s[q]];
                    float v10 = base[y1s[p] * 14 + x0s[q]];
                    float v11 = base[y1s[p] * 14 + x1s[q]];
                    sum += wy0s[p] * (wx0s[q] * v00 + wx1s[q] * v01) +
                           wy1s[p] * (wx0s[q] * v10 + wx1s[q] * v11);
                }
            }
        }
        mr[(size_t)(t * 49 + ij) * ND + o0 + c] = 0.25f * sum;
    }
}

// ---------------- GEMM 64x64 tile, BK=64, bf16 MFMA 16x16x32; fused BN + exact GELU + *mr (in place)
__global__ __launch_bounds__(256) void gemm_k(const unsigned short* __restrict__ Ap,
                                              const unsigned short* __restrict__ Bp,
                                              const float* __restrict__ cb,
                                              const float* __restrict__ gm,
                                              const float* __restrict__ bt,
                                              const float* __restrict__ rm,
                                              const float* __restrict__ rv,
                                              float* __restrict__ mrW) {
    __shared__ unsigned short As[64][72];   // pitch 72 bf16 = 144B -> 2-way banks on frag reads (free)
    __shared__ unsigned short Bs[64][72];
    const int tid = threadIdx.x;
    const int n0 = blockIdx.x * 64;
    const int m0 = blockIdx.y * 64;
    const int wave = tid >> 6;
    const int lane = tid & 63;
    const int wm = wave >> 1, wn = wave & 1;
    const int l15 = lane & 15, quad = lane >> 4;

    floatx4 acc00 = {0.f, 0.f, 0.f, 0.f}, acc01 = {0.f, 0.f, 0.f, 0.f};
    floatx4 acc10 = {0.f, 0.f, 0.f, 0.f}, acc11 = {0.f, 0.f, 0.f, 0.f};

    const int srow = tid >> 3;        // 0..31
    const int sko = (tid & 7) * 8;    // element offset, 16B chunks
    const float4* agp0 = (const float4*)(Ap + (size_t)(m0 + srow) * KD + sko);
    const float4* agp1 = (const float4*)(Ap + (size_t)(m0 + srow + 32) * KD + sko);
    const float4* bgp0 = (const float4*)(Bp + (size_t)(n0 + srow) * KD + sko);
    const float4* bgp1 = (const float4*)(Bp + (size_t)(n0 + srow + 32) * KD + sko);

    for (int kt = 0; kt < KD; kt += 64) {
        float4 av0 = agp0[kt >> 3];   // kt ushorts = kt/8 float4
        float4 av1 = agp1[kt >> 3];
        float4 bv0 = bgp0[kt >> 3];
        float4 bv1 = bgp1[kt >> 3];
        *(float4*)(&As[srow][sko]) = av0;
        *(float4*)(&As[srow + 32][sko]) = av1;
        *(float4*)(&Bs[srow][sko]) = bv0;
        *(float4*)(&Bs[srow + 32][sko]) = bv1;
        __syncthreads();
#pragma unroll
        for (int ko = 0; ko < 2; ++ko) {
            short8 a0 = *(const short8*)(&As[wm * 32 + l15][ko * 32 + quad * 8]);
            short8 a1 = *(const short8*)(&As[wm * 32 + 16 + l15][ko * 32 + quad * 8]);
            short8 b0 = *(const short8*)(&Bs[wn * 32 + l15][ko * 32 + quad * 8]);
            short8 b1 = *(const short8*)(&Bs[wn * 32 + 16 + l15][ko * 32 + quad * 8]);
            acc00 = __builtin_amdgcn_mfma_f32_16x16x32_bf16(a0, b0, acc00, 0, 0, 0);
            acc01 = __builtin_amdgcn_mfma_f32_16x16x32_bf16(a0, b1, acc01, 0, 0, 0);
            acc10 = __builtin_amdgcn_mfma_f32_16x16x32_bf16(a1, b0, acc10, 0, 0, 0);
            acc11 = __builtin_amdgcn_mfma_f32_16x16x32_bf16(a1, b1, acc11, 0, 0, 0);
        }
        __syncthreads();
    }

#pragma unroll
    for (int ni = 0; ni < 2; ++ni) {
        int n = n0 + wn * 32 + ni * 16 + l15;
        float scale = gm[n] / sqrtf(rv[n] + 1e-6f);
        float shift = (cb[n] - rm[n]) * scale + bt[n];
#pragma unroll
        for (int mi = 0; mi < 2; ++mi) {
            floatx4 a = (ni == 0) ? (mi == 0 ? acc00 : acc10) : (mi == 0 ? acc01 : acc11);
#pragma unroll
            for (int r = 0; r < 4; ++r) {
                int m = m0 + wm * 32 + mi * 16 + quad * 4 + r;
                if (m < MD) {
                    float v = a[r] * scale + shift;
                    float g = 0.5f * v * (1.0f + erff(v * 0.70710678118654752f));
                    size_t idx = (size_t)m * ND + n;
                    mrW[idx] = g * mrW[idx];
                }
            }
        }
    }
}

// ---------------- finalize: out = x_t + scatter(W)
__global__ __launch_bounds__(256) void final_k(const float* __restrict__ x_t,
                                               const float* __restrict__ rois,
                                               const float* __restrict__ W,
                                               float* __restrict__ out) {
    __shared__ int smt[TT], sml[TT];
    if (threadIdx.x < TT) {
        int t = threadIdx.x;
        float b0 = rois[t * 4 + 0] * 0.0625f, b1 = rois[t * 4 + 1] * 0.0625f;
        float b2 = rois[t * 4 + 2] * 0.0625f, b3 = rois[t * 4 + 3] * 0.0625f;
        int sxi = (int)floorf(b0), syi = (int)floorf(b1);
        int exi = (int)ceilf(b2), eyi = (int)ceilf(b3);
        int ml = (sxi + 7 < 14) ? sxi : exi - 7;
        int mt = (syi + 7 < 14) ? syi : eyi - 7;
        sml[t] = min(max(ml, 0), 7);   // dynamic_update_slice clamp
        smt[t] = min(max(mt, 0), 7);
    }
    __syncthreads();
    size_t idx4 = (size_t)blockIdx.x * 256 + threadIdx.x;
    size_t e0 = idx4 * 4;
    float4 xv = *(const float4*)(x_t + e0);
    float r[4] = {xv.x, xv.y, xv.z, xv.w};
    int o = (int)(e0 / 3136);
    int rme = (int)(e0 % 3136);
    int t = rme / 196;
    int pix = rme % 196;       // 4|196 -> same (o,t) for all 4 elements
    int mt = smt[t], ml = sml[t];
#pragma unroll
    for (int u = 0; u < 4; ++u) {
        int h = (pix + u) / 14, w = (pix + u) % 14;
        int i = h - mt, j = w - ml;
        if (i >= 0 && i < 7 && j >= 0 && j < 7)
            r[u] += W[(size_t)(t * 49 + i * 7 + j) * ND + o];
    }
    *(float4*)(out + e0) = make_float4(r[0], r[1], r[2], r[3]);
}

extern "C" void kernel_launch(void* const* d_in, const int* in_sizes, int n_in,
                              void* d_out, int out_size, void* d_ws, size_t ws_size,
                              hipStream_t stream) {
    const float* y = (const float*)d_in[0];
    const float* x_t = (const float*)d_in[1];
    const float* rois = (const float*)d_in[2];
    const float* conv_w = (const float*)d_in[3];
    const float* conv_b = (const float*)d_in[4];
    const float* gamma = (const float*)d_in[5];
    const float* beta = (const float*)d_in[6];
    const float* run_mean = (const float*)d_in[7];
    const float* run_var = (const float*)d_in[8];
    float* out = (float*)d_out;

    char* ws = (char*)d_ws;
    unsigned short* Ap = (unsigned short*)ws;                       // 832*1536*2   = 2,555,904 B
    unsigned short* Bp = (unsigned short*)(ws + 2555904);           // 3072*1536*2  = 9,437,184 B
    float* mrW = (float*)(ws + 2555904 + 9437184);                  // 784*3072*4   = 9,633,792 B
    // total ws use: 21,626,880 B

    packA_k<<<MPAD, 256, 0, stream>>>(y, Ap);
    packB_k<<<(ND * KD) / 1024, 256, 0, stream>>>(conv_w, Bp);
    roi_k<<<dim3(ND / 64, TT), 256, 0, stream>>>(x_t, rois, mrW);
    gemm_k<<<dim3(ND / 64, MPAD / 64), 256, 0, stream>>>(Ap, Bp, conv_b, gamma, beta,
                                                         run_mean, run_var, mrW);
    final_k<<<(3072 * 3136) / 1024, 256, 0, stream>>>(x_t, rois, mrW, out);
}

// Round 2
// 201.717 us; speedup vs baseline: 1.0541x; 1.0541x over previous
//
#include <hip/hip_runtime.h>

#define KD 1536
#define ND 3072
#define MD 784
#define MPAD 832
#define TT 16

// prep grid partition
#define NB_ROI 768              // 48 o-blocks x 16 t
#define NB_PACKA 832            // one block per m row
#define NB_PACKB 1152           // 4096 elements each
#define PREP_BLOCKS (NB_ROI + NB_PACKA + NB_PACKB)

typedef __attribute__((ext_vector_type(8))) short short8;
typedef __attribute__((ext_vector_type(4))) float floatx4;

__device__ __forceinline__ unsigned short f2bf(float f) {
    unsigned int x = __float_as_uint(f);
    unsigned int r = (x + 0x7fffu + ((x >> 16) & 1u)) >> 16;
    return (unsigned short)r;
}

// ---------------- prep: roi (blocks 0..767) | packA (768..1599) | packB (1600..2751)
__global__ __launch_bounds__(256) void prep_k(const float* __restrict__ y,
                                              const float* __restrict__ x_t,
                                              const float* __restrict__ rois,
                                              const float* __restrict__ conv_w,
                                              unsigned short* __restrict__ Ap,
                                              unsigned short* __restrict__ Bp,
                                              float* __restrict__ mr) {
    __shared__ float sm[64 * 197];
    __shared__ float wx0s[14], wx1s[14], wy0s[14], wy1s[14];
    __shared__ int x0s[14], x1s[14], y0s[14], y1s[14], vxs[14], vys[14];
    const int bid = blockIdx.x;
    const int tid = threadIdx.x;

    if (bid >= NB_ROI + NB_PACKA) {
        // ---- packB: conv_w fp32 [o][c] -> bf16 [ND][KD] (k contiguous)
        int pb = bid - (NB_ROI + NB_PACKA);
#pragma unroll
        for (int v = 0; v < 4; ++v) {
            size_t e = (size_t)pb * 4096 + v * 1024 + tid * 4;
            float4 w4 = *(const float4*)(conv_w + e);
            ushort4 o;
            o.x = f2bf(w4.x); o.y = f2bf(w4.y); o.z = f2bf(w4.z); o.w = f2bf(w4.w);
            *(ushort4*)(Bp + e) = o;
        }
        return;
    }
    if (bid >= NB_ROI) {
        // ---- packA: y fp32 [c][t][14][14] -> Ap bf16 [MPAD][KD], A[m][k]=y[k][t][2i][2j]
        int m = bid - NB_ROI;
        if (m >= MD) {
            for (int k = tid; k < KD; k += 256) Ap[(size_t)m * KD + k] = 0;
            return;
        }
        int t = m / 49, ij = m % 49, i = ij / 7, j = ij % 7;
        int off = t * 196 + (2 * i) * 14 + 2 * j;
        for (int k = tid; k < KD; k += 256)
            Ap[(size_t)m * KD + k] = f2bf(y[(size_t)k * 3136 + off]);
        return;
    }

    // ---- ROI align: x_t [o][t][14][14] -> mr [m][ND], m = t*49 + i*7 + j
    const int t = bid / 48;
    const int o0 = (bid % 48) * 64;

    if (tid < 14) {
        float b0 = rois[t * 4 + 0] * 0.0625f, b1 = rois[t * 4 + 1] * 0.0625f;
        float b2 = rois[t * 4 + 2] * 0.0625f, b3 = rois[t * 4 + 3] * 0.0625f;
        float rw = fmaxf(b2 - b0, 1.0f), rh = fmaxf(b3 - b1, 1.0f);
        float bw = rw * (1.0f / 7.0f), bh = rh * (1.0f / 7.0f);
        int p = tid;
        float pos = (float)(p >> 1) + 0.25f + 0.5f * (float)(p & 1);
        float xs = b0 + pos * bw;
        float ysv = b1 + pos * bh;
        vxs[p] = (xs >= -1.0f && xs <= 14.0f);
        vys[p] = (ysv >= -1.0f && ysv <= 14.0f);
        float xc = fminf(fmaxf(xs, 0.0f), 13.0f);
        float yc = fminf(fmaxf(ysv, 0.0f), 13.0f);
        int x0 = (int)floorf(xc), y0 = (int)floorf(yc);
        x0s[p] = x0; y0s[p] = y0;
        x1s[p] = min(x0 + 1, 13); y1s[p] = min(y0 + 1, 13);
        float lx = xc - (float)x0, ly = yc - (float)y0;
        wx0s[p] = 1.0f - lx; wx1s[p] = lx; wy0s[p] = 1.0f - ly; wy1s[p] = ly;
    }
    for (int f = tid; f < 64 * 196; f += 256) {
        int c = f / 196, pix = f % 196;
        sm[c * 197 + pix] = x_t[(size_t)(o0 + c) * 3136 + t * 196 + pix];
    }
    __syncthreads();
    for (int item = tid; item < 64 * 49; item += 256) {
        int c = item & 63, ij = item >> 6;
        int i = ij / 7, j = ij % 7;
        const float* base = &sm[c * 197];
        float sum = 0.0f;
#pragma unroll
        for (int s = 0; s < 2; ++s) {
            int p = 2 * i + s;
#pragma unroll
            for (int u = 0; u < 2; ++u) {
                int q = 2 * j + u;
                if (vys[p] && vxs[q]) {
                    float v00 = base[y0s[p] * 14 + x0s[q]];
                    float v01 = base[y0s[p] * 14 + x1s[q]];
                    float v10 = base[y1s[p] * 14 + x0s[q]];
                    float v11 = base[y1s[p] * 14 + x1s[q]];
                    sum += wy0s[p] * (wx0s[q] * v00 + wx1s[q] * v01) +
                           wy1s[p] * (wx0s[q] * v10 + wx1s[q] * v11);
                }
            }
        }
        mr[(size_t)(t * 49 + ij) * ND + o0 + c] = 0.25f * sum;
    }
}

// ---------------- GEMM 64x64 tile, BK=64, double-buffered LDS, one barrier/iter
// fused BN + exact GELU + *mr (in place)
__global__ __launch_bounds__(256) void gemm_k(const unsigned short* __restrict__ Ap,
                                              const unsigned short* __restrict__ Bp,
                                              const float* __restrict__ cb,
                                              const float* __restrict__ gm,
                                              const float* __restrict__ bt,
                                              const float* __restrict__ rm,
                                              const float* __restrict__ rv,
                                              float* __restrict__ mrW) {
    __shared__ unsigned short As[2][64][72];  // pitch 72 -> 2-way bank alias on frag reads (free)
    __shared__ unsigned short Bs[2][64][72];
    const int tid = threadIdx.x;
    const int n0 = blockIdx.x * 64;
    const int m0 = blockIdx.y * 64;
    const int wave = tid >> 6;
    const int lane = tid & 63;
    const int wm = wave >> 1, wn = wave & 1;
    const int l15 = lane & 15, quad = lane >> 4;

    floatx4 acc00 = {0.f, 0.f, 0.f, 0.f}, acc01 = {0.f, 0.f, 0.f, 0.f};
    floatx4 acc10 = {0.f, 0.f, 0.f, 0.f}, acc11 = {0.f, 0.f, 0.f, 0.f};

    const int srow = tid >> 3;        // 0..31
    const int sko = (tid & 7) * 8;    // bf16-element offset of this thread's 16B chunk
    const float4* agp0 = (const float4*)(Ap + (size_t)(m0 + srow) * KD + sko);
    const float4* agp1 = (const float4*)(Ap + (size_t)(m0 + srow + 32) * KD + sko);
    const float4* bgp0 = (const float4*)(Bp + (size_t)(n0 + srow) * KD + sko);
    const float4* bgp1 = (const float4*)(Bp + (size_t)(n0 + srow + 32) * KD + sko);

    // preload tile 0
    float4 av0 = agp0[0], av1 = agp1[0], bv0 = bgp0[0], bv1 = bgp1[0];

    int p = 0;
    for (int kt = 0; kt < KD; kt += 64, p ^= 1) {
        *(float4*)(&As[p][srow][sko]) = av0;
        *(float4*)(&As[p][srow + 32][sko]) = av1;
        *(float4*)(&Bs[p][srow][sko]) = bv0;
        *(float4*)(&Bs[p][srow + 32][sko]) = bv1;
        __syncthreads();
        if (kt + 64 < KD) {           // prefetch next tile; overlaps with MFMA below
            int q = (kt >> 3) + 8;
            av0 = agp0[q]; av1 = agp1[q]; bv0 = bgp0[q]; bv1 = bgp1[q];
        }
#pragma unroll
        for (int ko = 0; ko < 2; ++ko) {
            short8 a0 = *(const short8*)(&As[p][wm * 32 + l15][ko * 32 + quad * 8]);
            short8 a1 = *(const short8*)(&As[p][wm * 32 + 16 + l15][ko * 32 + quad * 8]);
            short8 b0 = *(const short8*)(&Bs[p][wn * 32 + l15][ko * 32 + quad * 8]);
            short8 b1 = *(const short8*)(&Bs[p][wn * 32 + 16 + l15][ko * 32 + quad * 8]);
            acc00 = __builtin_amdgcn_mfma_f32_16x16x32_bf16(a0, b0, acc00, 0, 0, 0);
            acc01 = __builtin_amdgcn_mfma_f32_16x16x32_bf16(a0, b1, acc01, 0, 0, 0);
            acc10 = __builtin_amdgcn_mfma_f32_16x16x32_bf16(a1, b0, acc10, 0, 0, 0);
            acc11 = __builtin_amdgcn_mfma_f32_16x16x32_bf16(a1, b1, acc11, 0, 0, 0);
        }
        // no second barrier: next iter writes the OTHER buffer; barrier above separates
        // this iter's writes from last iter's reads of the same buffer.
    }

#pragma unroll
    for (int ni = 0; ni < 2; ++ni) {
        int n = n0 + wn * 32 + ni * 16 + l15;
        float scale = gm[n] / sqrtf(rv[n] + 1e-6f);
        float shift = (cb[n] - rm[n]) * scale + bt[n];
#pragma unroll
        for (int mi = 0; mi < 2; ++mi) {
            floatx4 a = (ni == 0) ? (mi == 0 ? acc00 : acc10) : (mi == 0 ? acc01 : acc11);
#pragma unroll
            for (int r = 0; r < 4; ++r) {
                int m = m0 + wm * 32 + mi * 16 + quad * 4 + r;
                if (m < MD) {
                    float v = a[r] * scale + shift;
                    float g = 0.5f * v * (1.0f + erff(v * 0.70710678118654752f));
                    size_t idx = (size_t)m * ND + n;
                    mrW[idx] = g * mrW[idx];
                }
            }
        }
    }
}

// ---------------- finalize: out = x_t + scatter(W)
__global__ __launch_bounds__(256) void final_k(const float* __restrict__ x_t,
                                               const float* __restrict__ rois,
                                               const float* __restrict__ W,
                                               float* __restrict__ out) {
    __shared__ int smt[TT], sml[TT];
    if (threadIdx.x < TT) {
        int t = threadIdx.x;
        float b0 = rois[t * 4 + 0] * 0.0625f, b1 = rois[t * 4 + 1] * 0.0625f;
        float b2 = rois[t * 4 + 2] * 0.0625f, b3 = rois[t * 4 + 3] * 0.0625f;
        int sxi = (int)floorf(b0), syi = (int)floorf(b1);
        int exi = (int)ceilf(b2), eyi = (int)ceilf(b3);
        int ml = (sxi + 7 < 14) ? sxi : exi - 7;
        int mt = (syi + 7 < 14) ? syi : eyi - 7;
        sml[t] = min(max(ml, 0), 7);   // dynamic_update_slice clamp
        smt[t] = min(max(mt, 0), 7);
    }
    __syncthreads();
    size_t idx4 = (size_t)blockIdx.x * 256 + threadIdx.x;
    size_t e0 = idx4 * 4;
    float4 xv = *(const float4*)(x_t + e0);
    float r[4] = {xv.x, xv.y, xv.z, xv.w};
    int o = (int)(e0 / 3136);
    int rme = (int)(e0 % 3136);
    int t = rme / 196;
    int pix = rme % 196;       // 4|196 -> same (o,t) for all 4 elements
    int mt = smt[t], ml = sml[t];
#pragma unroll
    for (int u = 0; u < 4; ++u) {
        int h = (pix + u) / 14, w = (pix + u) % 14;
        int i = h - mt, j = w - ml;
        if (i >= 0 && i < 7 && j >= 0 && j < 7)
            r[u] += W[(size_t)(t * 49 + i * 7 + j) * ND + o];
    }
    *(float4*)(out + e0) = make_float4(r[0], r[1], r[2], r[3]);
}

extern "C" void kernel_launch(void* const* d_in, const int* in_sizes, int n_in,
                              void* d_out, int out_size, void* d_ws, size_t ws_size,
                              hipStream_t stream) {
    const float* y = (const float*)d_in[0];
    const float* x_t = (const float*)d_in[1];
    const float* rois = (const float*)d_in[2];
    const float* conv_w = (const float*)d_in[3];
    const float* conv_b = (const float*)d_in[4];
    const float* gamma = (const float*)d_in[5];
    const float* beta = (const float*)d_in[6];
    const float* run_mean = (const float*)d_in[7];
    const float* run_var = (const float*)d_in[8];
    float* out = (float*)d_out;

    char* ws = (char*)d_ws;
    unsigned short* Ap = (unsigned short*)ws;                       // 832*1536*2   = 2,555,904 B
    unsigned short* Bp = (unsigned short*)(ws + 2555904);           // 3072*1536*2  = 9,437,184 B
    float* mrW = (float*)(ws + 2555904 + 9437184);                  // 784*3072*4   = 9,633,792 B
    // total ws use: 21,626,880 B

    prep_k<<<PREP_BLOCKS, 256, 0, stream>>>(y, x_t, rois, conv_w, Ap, Bp, mrW);
    gemm_k<<<dim3(ND / 64, MPAD / 64), 256, 0, stream>>>(Ap, Bp, conv_b, gamma, beta,
                                                         run_mean, run_var, mrW);
    final_k<<<(3072 * 3136) / 1024, 256, 0, stream>>>(x_t, rois, mrW, out);
}

// Round 3
// 177.814 us; speedup vs baseline: 1.1958x; 1.1344x over previous
//
#include <hip/hip_runtime.h>

#define KD 1536
#define ND 3072
#define MD 784
#define MPAD 832
#define TT 16

// prep grid partition
#define NB_ROI 768               // 16 t x 48 o-blocks
#define NB_PACKA 384             // 16 t x 24 k-chunks (64 ch each)
#define NB_ZERO 1                // Ap rows 784..831
#define NB_PACKB 1152            // 4096 elements each
#define PREP_BLOCKS (NB_ROI + NB_PACKA + NB_ZERO + NB_PACKB)

typedef __attribute__((ext_vector_type(8))) short short8;
typedef __attribute__((ext_vector_type(4))) float floatx4;

__device__ __forceinline__ unsigned short f2bf(float f) {
    unsigned int x = __float_as_uint(f);
    unsigned int r = (x + 0x7fffu + ((x >> 16) & 1u)) >> 16;
    return (unsigned short)r;
}

// ---------------- prep: roi | packA | zerofill | packB
__global__ __launch_bounds__(256) void prep_k(const float* __restrict__ y,
                                              const float* __restrict__ x_t,
                                              const float* __restrict__ rois,
                                              const float* __restrict__ conv_w,
                                              unsigned short* __restrict__ Ap,
                                              unsigned short* __restrict__ Bp,
                                              float* __restrict__ mr) {
    __shared__ float sm[64 * 197];
    __shared__ float wx0s[14], wx1s[14], wy0s[14], wy1s[14];
    __shared__ int x0s[14], x1s[14], y0s[14], y1s[14], vxs[14], vys[14];
    const int bid = blockIdx.x;
    const int tid = threadIdx.x;

    if (bid >= NB_ROI + NB_PACKA + NB_ZERO) {
        // ---- packB: conv_w fp32 [o][c] -> bf16 [ND][KD] (k contiguous), fully coalesced
        int pb = bid - (NB_ROI + NB_PACKA + NB_ZERO);
#pragma unroll
        for (int v = 0; v < 4; ++v) {
            size_t e = (size_t)pb * 4096 + v * 1024 + tid * 4;
            float4 w4 = *(const float4*)(conv_w + e);
            ushort4 o;
            o.x = f2bf(w4.x); o.y = f2bf(w4.y); o.z = f2bf(w4.z); o.w = f2bf(w4.w);
            *(ushort4*)(Bp + e) = o;
        }
        return;
    }
    if (bid == NB_ROI + NB_PACKA) {
        // ---- zero-fill Ap rows 784..831
        uint4 z = {0u, 0u, 0u, 0u};
        uint4* dst = (uint4*)(Ap + (size_t)MD * KD);
        for (int v = tid; v < (MPAD - MD) * KD / 8; v += 256) dst[v] = z;
        return;
    }
    if (bid >= NB_ROI) {
        // ---- packA: block = (t, kc). Coalesced frame-major read of y into LDS,
        //      then scatter 49 even pixels to Ap[m][k] with lanes over k.
        int p = bid - NB_ROI;
        int t = p / 24, kc = p % 24;
        for (int f = tid; f < 64 * 196; f += 256) {
            int c = f / 196, pix = f % 196;
            sm[c * 197 + pix] = y[(size_t)(kc * 64 + c) * 3136 + t * 196 + pix];
        }
        __syncthreads();
        for (int item = tid; item < 64 * 49; item += 256) {
            int c = item & 63, ij = item >> 6;
            int i = ij / 7, j = ij % 7;
            Ap[(size_t)(t * 49 + ij) * KD + kc * 64 + c] =
                f2bf(sm[c * 197 + (2 * i) * 14 + 2 * j]);
        }
        return;
    }

    // ---- ROI align: x_t [o][t][14][14] -> mr [m][ND], m = t*49 + i*7 + j
    const int t = bid / 48;
    const int o0 = (bid % 48) * 64;

    if (tid < 14) {
        float b0 = rois[t * 4 + 0] * 0.0625f, b1 = rois[t * 4 + 1] * 0.0625f;
        float b2 = rois[t * 4 + 2] * 0.0625f, b3 = rois[t * 4 + 3] * 0.0625f;
        float rw = fmaxf(b2 - b0, 1.0f), rh = fmaxf(b3 - b1, 1.0f);
        float bw = rw * (1.0f / 7.0f), bh = rh * (1.0f / 7.0f);
        int p = tid;
        float pos = (float)(p >> 1) + 0.25f + 0.5f * (float)(p & 1);
        float xs = b0 + pos * bw;
        float ysv = b1 + pos * bh;
        vxs[p] = (xs >= -1.0f && xs <= 14.0f);
        vys[p] = (ysv >= -1.0f && ysv <= 14.0f);
        float xc = fminf(fmaxf(xs, 0.0f), 13.0f);
        float yc = fminf(fmaxf(ysv, 0.0f), 13.0f);
        int x0 = (int)floorf(xc), y0 = (int)floorf(yc);
        x0s[p] = x0; y0s[p] = y0;
        x1s[p] = min(x0 + 1, 13); y1s[p] = min(y0 + 1, 13);
        float lx = xc - (float)x0, ly = yc - (float)y0;
        wx0s[p] = 1.0f - lx; wx1s[p] = lx; wy0s[p] = 1.0f - ly; wy1s[p] = ly;
    }
    for (int f = tid; f < 64 * 196; f += 256) {
        int c = f / 196, pix = f % 196;
        sm[c * 197 + pix] = x_t[(size_t)(o0 + c) * 3136 + t * 196 + pix];
    }
    __syncthreads();
    for (int item = tid; item < 64 * 49; item += 256) {
        int c = item & 63, ij = item >> 6;
        int i = ij / 7, j = ij % 7;
        const float* base = &sm[c * 197];
        float sum = 0.0f;
#pragma unroll
        for (int s = 0; s < 2; ++s) {
            int p = 2 * i + s;
#pragma unroll
            for (int u = 0; u < 2; ++u) {
                int q = 2 * j + u;
                if (vys[p] && vxs[q]) {
                    float v00 = base[y0s[p] * 14 + x0s[q]];
                    float v01 = base[y0s[p] * 14 + x1s[q]];
                    float v10 = base[y1s[p] * 14 + x0s[q]];
                    float v11 = base[y1s[p] * 14 + x1s[q]];
                    sum += wy0s[p] * (wx0s[q] * v00 + wx1s[q] * v01) +
                           wy1s[p] * (wx0s[q] * v10 + wx1s[q] * v11);
                }
            }
        }
        mr[(size_t)(t * 49 + ij) * ND + o0 + c] = 0.25f * sum;
    }
}

// ---------------- GEMM 64x64 tile, BK=64, double-buffered LDS, one barrier/iter
// fused BN + exact GELU + *mr (in place)
__global__ __launch_bounds__(256) void gemm_k(const unsigned short* __restrict__ Ap,
                                              const unsigned short* __restrict__ Bp,
                                              const float* __restrict__ cb,
                                              const float* __restrict__ gm,
                                              const float* __restrict__ bt,
                                              const float* __restrict__ rm,
                                              const float* __restrict__ rv,
                                              float* __restrict__ mrW) {
    __shared__ unsigned short As[2][64][72];
    __shared__ unsigned short Bs[2][64][72];
    const int tid = threadIdx.x;
    const int n0 = blockIdx.x * 64;
    const int m0 = blockIdx.y * 64;
    const int wave = tid >> 6;
    const int lane = tid & 63;
    const int wm = wave >> 1, wn = wave & 1;
    const int l15 = lane & 15, quad = lane >> 4;

    floatx4 acc00 = {0.f, 0.f, 0.f, 0.f}, acc01 = {0.f, 0.f, 0.f, 0.f};
    floatx4 acc10 = {0.f, 0.f, 0.f, 0.f}, acc11 = {0.f, 0.f, 0.f, 0.f};

    const int srow = tid >> 3;
    const int sko = (tid & 7) * 8;
    const float4* agp0 = (const float4*)(Ap + (size_t)(m0 + srow) * KD + sko);
    const float4* agp1 = (const float4*)(Ap + (size_t)(m0 + srow + 32) * KD + sko);
    const float4* bgp0 = (const float4*)(Bp + (size_t)(n0 + srow) * KD + sko);
    const float4* bgp1 = (const float4*)(Bp + (size_t)(n0 + srow + 32) * KD + sko);

    float4 av0 = agp0[0], av1 = agp1[0], bv0 = bgp0[0], bv1 = bgp1[0];

    int p = 0;
    for (int kt = 0; kt < KD; kt += 64, p ^= 1) {
        *(float4*)(&As[p][srow][sko]) = av0;
        *(float4*)(&As[p][srow + 32][sko]) = av1;
        *(float4*)(&Bs[p][srow][sko]) = bv0;
        *(float4*)(&Bs[p][srow + 32][sko]) = bv1;
        __syncthreads();
        if (kt + 64 < KD) {
            int q = (kt >> 3) + 8;
            av0 = agp0[q]; av1 = agp1[q]; bv0 = bgp0[q]; bv1 = bgp1[q];
        }
#pragma unroll
        for (int ko = 0; ko < 2; ++ko) {
            short8 a0 = *(const short8*)(&As[p][wm * 32 + l15][ko * 32 + quad * 8]);
            short8 a1 = *(const short8*)(&As[p][wm * 32 + 16 + l15][ko * 32 + quad * 8]);
            short8 b0 = *(const short8*)(&Bs[p][wn * 32 + l15][ko * 32 + quad * 8]);
            short8 b1 = *(const short8*)(&Bs[p][wn * 32 + 16 + l15][ko * 32 + quad * 8]);
            acc00 = __builtin_amdgcn_mfma_f32_16x16x32_bf16(a0, b0, acc00, 0, 0, 0);
            acc01 = __builtin_amdgcn_mfma_f32_16x16x32_bf16(a0, b1, acc01, 0, 0, 0);
            acc10 = __builtin_amdgcn_mfma_f32_16x16x32_bf16(a1, b0, acc10, 0, 0, 0);
            acc11 = __builtin_amdgcn_mfma_f32_16x16x32_bf16(a1, b1, acc11, 0, 0, 0);
        }
    }

#pragma unroll
    for (int ni = 0; ni < 2; ++ni) {
        int n = n0 + wn * 32 + ni * 16 + l15;
        float scale = gm[n] / sqrtf(rv[n] + 1e-6f);
        float shift = (cb[n] - rm[n]) * scale + bt[n];
#pragma unroll
        for (int mi = 0; mi < 2; ++mi) {
            floatx4 a = (ni == 0) ? (mi == 0 ? acc00 : acc10) : (mi == 0 ? acc01 : acc11);
#pragma unroll
            for (int r = 0; r < 4; ++r) {
                int m = m0 + wm * 32 + mi * 16 + quad * 4 + r;
                if (m < MD) {
                    float v = a[r] * scale + shift;
                    float g = 0.5f * v * (1.0f + erff(v * 0.70710678118654752f));
                    size_t idx = (size_t)m * ND + n;
                    mrW[idx] = g * mrW[idx];
                }
            }
        }
    }
}

// ---------------- finalize: out = x_t + scatter(W); block = (t, 64-channel chunk)
__global__ __launch_bounds__(256) void final_k(const float* __restrict__ x_t,
                                               const float* __restrict__ rois,
                                               const float* __restrict__ W,
                                               float* __restrict__ out) {
    __shared__ float Wl[49 * 65];   // pitch 65: bank = (ij + c) % 32, conflict-free
    const int o0 = blockIdx.x * 64;
    const int t = blockIdx.y;
    const int tid = threadIdx.x;

    // wave-uniform ROI box (every thread computes; cheap)
    float b0 = rois[t * 4 + 0] * 0.0625f, b1 = rois[t * 4 + 1] * 0.0625f;
    float b2 = rois[t * 4 + 2] * 0.0625f, b3 = rois[t * 4 + 3] * 0.0625f;
    int sxi = (int)floorf(b0), syi = (int)floorf(b1);
    int exi = (int)ceilf(b2), eyi = (int)ceilf(b3);
    int ml = (sxi + 7 < 14) ? sxi : exi - 7;
    int mt = (syi + 7 < 14) ? syi : eyi - 7;
    ml = min(max(ml, 0), 7);
    mt = min(max(mt, 0), 7);

    // stage W[t*49+ij][o0+c] coalesced (lanes over c)
    for (int idx = tid; idx < 49 * 64; idx += 256) {
        int c = idx & 63, ij = idx >> 6;
        Wl[ij * 65 + c] = W[(size_t)(t * 49 + ij) * ND + o0 + c];
    }
    __syncthreads();

    // stream x_t -> out, float4, coalesced; 3136 float4 items = 64 ch x 49
    for (int i4 = tid; i4 < 3136; i4 += 256) {
        int c = i4 / 49, p4 = i4 % 49;
        size_t e0 = (size_t)(o0 + c) * 3136 + t * 196 + p4 * 4;
        float4 xv = *(const float4*)(x_t + e0);
        float r[4] = {xv.x, xv.y, xv.z, xv.w};
#pragma unroll
        for (int u = 0; u < 4; ++u) {
            int pix = p4 * 4 + u;
            int h = pix / 14, w = pix % 14;
            int i = h - mt, j = w - ml;
            if (i >= 0 && i < 7 && j >= 0 && j < 7)
                r[u] += Wl[(i * 7 + j) * 65 + c];
        }
        *(float4*)(out + e0) = make_float4(r[0], r[1], r[2], r[3]);
    }
}

extern "C" void kernel_launch(void* const* d_in, const int* in_sizes, int n_in,
                              void* d_out, int out_size, void* d_ws, size_t ws_size,
                              hipStream_t stream) {
    const float* y = (const float*)d_in[0];
    const float* x_t = (const float*)d_in[1];
    const float* rois = (const float*)d_in[2];
    const float* conv_w = (const float*)d_in[3];
    const float* conv_b = (const float*)d_in[4];
    const float* gamma = (const float*)d_in[5];
    const float* beta = (const float*)d_in[6];
    const float* run_mean = (const float*)d_in[7];
    const float* run_var = (const float*)d_in[8];
    float* out = (float*)d_out;

    char* ws = (char*)d_ws;
    unsigned short* Ap = (unsigned short*)ws;                       // 832*1536*2   = 2,555,904 B
    unsigned short* Bp = (unsigned short*)(ws + 2555904);           // 3072*1536*2  = 9,437,184 B
    float* mrW = (float*)(ws + 2555904 + 9437184);                  // 784*3072*4   = 9,633,792 B

    prep_k<<<PREP_BLOCKS, 256, 0, stream>>>(y, x_t, rois, conv_w, Ap, Bp, mrW);
    gemm_k<<<dim3(ND / 64, MPAD / 64), 256, 0, stream>>>(Ap, Bp, conv_b, gamma, beta,
                                                         run_mean, run_var, mrW);
    final_k<<<dim3(ND / 64, TT), 256, 0, stream>>>(x_t, rois, mrW, out);
}